// Round 4
// baseline (397.468 us; speedup 1.0000x reference)
//
#include <hip/hip_runtime.h>
#include <stdint.h>

#define T_TOK 4096
#define DM    512
#define DFF   2048
#define NE    16
#define NSLOT (T_TOK * 2)
#define NW    (NE * DFF * DM)
#define MAXT64 144              // max sum ceil(cnt_e/64) = 128 + 16

typedef __attribute__((ext_vector_type(8))) short  bf16x8;
typedef __attribute__((ext_vector_type(4))) float  f32x4;
typedef __attribute__((ext_vector_type(8))) unsigned short us8;

static __device__ __forceinline__ unsigned short f2bf(float f) {
    unsigned int u = __float_as_uint(f);
    u += 0x7FFFu + ((u >> 16) & 1u);   // RNE
    return (unsigned short)(u >> 16);
}

// ------------- convert: w1, w2 fp32 -> bf16 (memory-bound) ---------------
__global__ __launch_bounds__(256) void convert_kernel(
    const float* __restrict__ w1, const float* __restrict__ w2,
    unsigned short* __restrict__ w1b, unsigned short* __restrict__ w2b)
{
    size_t i = ((size_t)blockIdx.x * 256 + threadIdx.x) * 8;
    const float* src; unsigned short* dst;
    if (i < (size_t)NW) { src = w1 + i;        dst = w1b + i; }
    else                { src = w2 + (i - NW); dst = w2b + (i - NW); }
    f32x4 a = *(const f32x4*)src;
    f32x4 b = *(const f32x4*)(src + 4);
    us8 v;
    v[0] = f2bf(a.x); v[1] = f2bf(a.y); v[2] = f2bf(a.z); v[3] = f2bf(a.w);
    v[4] = f2bf(b.x); v[5] = f2bf(b.y); v[6] = f2bf(b.z); v[7] = f2bf(b.w);
    *(us8*)dst = v;
}

// ------- router: fp32 logits, softmax, top-2; also emits x in bf16 -------
__global__ __launch_bounds__(256) void router_kernel(
    const float* __restrict__ x, const float* __restrict__ rw,
    const float* __restrict__ rb, int* __restrict__ tok_e,
    float* __restrict__ tok_g, unsigned short* __restrict__ xb)
{
    __shared__ float rws[NE * DM];
    int tid = threadIdx.x;
    for (int i = 0; i < 8; ++i) {
        int idx = (tid + i * 256) * 4;
        *(f32x4*)&rws[idx] = *(const f32x4*)&rw[idx];
    }
    __syncthreads();

    int wid = tid >> 6, lane = tid & 63;
    int t = blockIdx.x * 4 + wid;

    float xv[8];
    const float* xp = x + (size_t)t * DM + lane * 8;
    *(f32x4*)&xv[0] = *(const f32x4*)xp;
    *(f32x4*)&xv[4] = *(const f32x4*)(xp + 4);

    us8 v;
    for (int i = 0; i < 8; ++i) v[i] = f2bf(xv[i]);
    *(us8*)&xb[(size_t)t * DM + lane * 8] = v;

    float acc[NE];
    for (int e = 0; e < NE; ++e) {
        const float* wp = &rws[e * DM + lane * 8];
        float a = 0.f;
        for (int i = 0; i < 8; ++i) a += xv[i] * wp[i];
        acc[e] = a;
    }
    for (int e = 0; e < NE; ++e) {
        float v2 = acc[e];
        for (int off = 32; off > 0; off >>= 1) v2 += __shfl_xor(v2, off);
        acc[e] = v2 + rb[e];
    }
    float m = acc[0];
    for (int e = 1; e < NE; ++e) m = fmaxf(m, acc[e]);
    float p[NE]; float s = 0.f;
    for (int e = 0; e < NE; ++e) { p[e] = expf(acc[e] - m); s += p[e]; }
    float inv = 1.f / s;
    int i0 = 0; float p0 = p[0];
    for (int e = 1; e < NE; ++e) if (p[e] > p0) { p0 = p[e]; i0 = e; }
    int i1 = (i0 == 0) ? 1 : 0; float p1 = p[i1];
    for (int e = 0; e < NE; ++e)
        if (e != i0 && p[e] > p1) { p1 = p[e]; i1 = e; }
    if (lane == 0) {
        tok_e[t * 2]     = i0;  tok_e[t * 2 + 1] = i1;
        tok_g[t * 2]     = p0 * inv;
        tok_g[t * 2 + 1] = p1 * inv;
    }
}

// -------- compaction: slot lists + 64-row tile prefix + tok->slot --------
// eoff: [0..15] row offset, [16..31] count, [32..47] tile_base, [48] total
__global__ __launch_bounds__(256) void compact_kernel(
    const int* __restrict__ tok_e, int* __restrict__ slot_token,
    int* __restrict__ tok_slot, int* __restrict__ eoff)
{
    __shared__ int cnt[NE], cur[NE];
    int tid = threadIdx.x;
    if (tid < NE) cnt[tid] = 0;
    __syncthreads();
    for (int t = tid; t < T_TOK; t += 256) {
        atomicAdd(&cnt[tok_e[t * 2]], 1);
        atomicAdd(&cnt[tok_e[t * 2 + 1]], 1);
    }
    __syncthreads();
    if (tid == 0) {
        int r = 0, tb = 0;
        for (int e = 0; e < NE; ++e) {
            eoff[e] = r; cur[e] = r; r += cnt[e];
            eoff[16 + e] = cnt[e];
            eoff[32 + e] = tb; tb += (cnt[e] + 63) >> 6;
        }
        eoff[48] = tb;
    }
    __syncthreads();
    for (int t = tid; t < T_TOK; t += 256) {
        for (int k = 0; k < 2; ++k) {
            int e = tok_e[t * 2 + k];
            int s = atomicAdd(&cur[e], 1);
            slot_token[s]       = t;
            tok_slot[t * 2 + k] = s;
        }
    }
}

// ---- GEMM1: LDS-free register-tile. wave = 64 rows x 64 cols ------------
// grid (DFF/256=8, MAXT64). Per kt: 16 direct dwordx4 frag loads + 32 MFMA.
__global__ __launch_bounds__(256) void gemm1_kernel(
    const unsigned short* __restrict__ xb, const unsigned short* __restrict__ w1b,
    const float* __restrict__ b1, const int* __restrict__ slot_token,
    const int* __restrict__ eoff, unsigned short* __restrict__ h)
{
    __shared__ unsigned short bounce[4][64 * 68];
    int tid = threadIdx.x, wave = tid >> 6, l = tid & 63;
    int c = l & 15, q = l >> 4;

    int ty = blockIdx.y;
    int e = 0;
    #pragma unroll
    for (int k = 1; k < NE; ++k) e += (eoff[32 + k] <= ty) ? 1 : 0;
    if (ty >= eoff[48]) return;
    int off = eoff[e], cnt = eoff[16 + e];
    int mt  = ty - eoff[32 + e];
    int row0  = off + mt * 64;
    int valid = cnt - mt * 64; if (valid > 64) valid = 64;
    int nW = blockIdx.x * 256 + wave * 64;

    const unsigned short* pA[4];
    const unsigned short* pB[4];
    int smax = off + cnt - 1;
    #pragma unroll
    for (int i = 0; i < 4; ++i) {
        int s = row0 + i * 16 + c; if (s > smax) s = smax;
        pA[i] = xb + (size_t)slot_token[s] * DM + q * 8;
    }
    #pragma unroll
    for (int j = 0; j < 4; ++j)
        pB[j] = w1b + ((size_t)e * DFF + nW + j * 16 + c) * DM + q * 8;

    f32x4 acc[16];
    #pragma unroll
    for (int i = 0; i < 16; ++i) acc[i] = (f32x4){0.f, 0.f, 0.f, 0.f};

    #pragma unroll 2
    for (int kt = 0; kt < DM / 64; ++kt) {
        bf16x8 a0[4], a1[4], b0[4], b1v[4];
        #pragma unroll
        for (int i = 0; i < 4; ++i) {
            a0[i] = *(const bf16x8*)(pA[i] + kt * 64);
            a1[i] = *(const bf16x8*)(pA[i] + kt * 64 + 32);
        }
        #pragma unroll
        for (int j = 0; j < 4; ++j) {
            b0[j]  = *(const bf16x8*)(pB[j] + kt * 64);
            b1v[j] = *(const bf16x8*)(pB[j] + kt * 64 + 32);
        }
        #pragma unroll
        for (int i = 0; i < 4; ++i)
            #pragma unroll
            for (int j = 0; j < 4; ++j)
                acc[i * 4 + j] = __builtin_amdgcn_mfma_f32_16x16x32_bf16(
                    a0[i], b0[j], acc[i * 4 + j], 0, 0, 0);
        #pragma unroll
        for (int i = 0; i < 4; ++i)
            #pragma unroll
            for (int j = 0; j < 4; ++j)
                acc[i * 4 + j] = __builtin_amdgcn_mfma_f32_16x16x32_bf16(
                    a1[i], b1v[j], acc[i * 4 + j], 0, 0, 0);
    }

    // epilogue: bias + exact gelu -> per-wave LDS bounce (no barrier)
    float bias[4];
    #pragma unroll
    for (int j = 0; j < 4; ++j) bias[j] = b1[e * DFF + nW + j * 16 + c];
    unsigned short* bw = bounce[wave];
    #pragma unroll
    for (int i = 0; i < 4; ++i)
        #pragma unroll
        for (int j = 0; j < 4; ++j) {
            f32x4 a = acc[i * 4 + j];
            #pragma unroll
            for (int r = 0; r < 4; ++r) {
                float z = a[r] + bias[j];
                float g = 0.5f * z * (1.f + erff(z * 0.70710678118654752f));
                bw[(i * 16 + q * 4 + r) * 68 + j * 16 + c] = f2bf(g);
            }
        }
    __asm__ volatile("s_waitcnt lgkmcnt(0)" ::: "memory");
    #pragma unroll
    for (int it = 0; it < 8; ++it) {
        int row = it * 8 + (l >> 3);
        if (row < valid)
            *(us8*)&h[(size_t)(row0 + row) * DFF + nW + (l & 7) * 8] =
                *(us8*)&bw[row * 68 + (l & 7) * 8];
    }
}

// ---- GEMM2: LDS-free register-tile, K-split x2 into y[2] ----------------
// grid (4, MAXT64): bx>>1 = K-half, bx&1 = n-block(256). wave tile 64x64.
__global__ __launch_bounds__(256) void gemm2_kernel(
    const unsigned short* __restrict__ h, const unsigned short* __restrict__ w2b,
    const int* __restrict__ eoff, float* __restrict__ y)
{
    int tid = threadIdx.x, wave = tid >> 6, l = tid & 63;
    int c = l & 15, q = l >> 4;

    int ty = blockIdx.y;
    int e = 0;
    #pragma unroll
    for (int k = 1; k < NE; ++k) e += (eoff[32 + k] <= ty) ? 1 : 0;
    if (ty >= eoff[48]) return;
    int off = eoff[e], cnt = eoff[16 + e];
    int mt  = ty - eoff[32 + e];
    int row0  = off + mt * 64;
    int valid = cnt - mt * 64; if (valid > 64) valid = 64;
    int half = blockIdx.x >> 1;
    int nW   = (blockIdx.x & 1) * 256 + wave * 64;
    int k0   = half * (DFF / 2);

    const unsigned short* pA[4];
    const unsigned short* pB[4];
    int smax = off + cnt - 1;
    #pragma unroll
    for (int i = 0; i < 4; ++i) {
        int s = row0 + i * 16 + c; if (s > smax) s = smax;
        pA[i] = h + (size_t)s * DFF + k0 + q * 8;
    }
    #pragma unroll
    for (int j = 0; j < 4; ++j)
        pB[j] = w2b + ((size_t)e * DM + nW + j * 16 + c) * DFF + k0 + q * 8;

    f32x4 acc[16];
    #pragma unroll
    for (int i = 0; i < 16; ++i) acc[i] = (f32x4){0.f, 0.f, 0.f, 0.f};

    #pragma unroll 2
    for (int kt = 0; kt < (DFF / 2) / 64; ++kt) {
        bf16x8 a0[4], a1[4], b0[4], b1v[4];
        #pragma unroll
        for (int i = 0; i < 4; ++i) {
            a0[i] = *(const bf16x8*)(pA[i] + kt * 64);
            a1[i] = *(const bf16x8*)(pA[i] + kt * 64 + 32);
        }
        #pragma unroll
        for (int j = 0; j < 4; ++j) {
            b0[j]  = *(const bf16x8*)(pB[j] + kt * 64);
            b1v[j] = *(const bf16x8*)(pB[j] + kt * 64 + 32);
        }
        #pragma unroll
        for (int i = 0; i < 4; ++i)
            #pragma unroll
            for (int j = 0; j < 4; ++j)
                acc[i * 4 + j] = __builtin_amdgcn_mfma_f32_16x16x32_bf16(
                    a0[i], b0[j], acc[i * 4 + j], 0, 0, 0);
        #pragma unroll
        for (int i = 0; i < 4; ++i)
            #pragma unroll
            for (int j = 0; j < 4; ++j)
                acc[i * 4 + j] = __builtin_amdgcn_mfma_f32_16x16x32_bf16(
                    a1[i], b1v[j], acc[i * 4 + j], 0, 0, 0);
    }

    float* yb = y + (size_t)half * NSLOT * DM;
    #pragma unroll
    for (int i = 0; i < 4; ++i)
        #pragma unroll
        for (int j = 0; j < 4; ++j)
            #pragma unroll
            for (int r = 0; r < 4; ++r) {
                int row = i * 16 + q * 4 + r;
                if (row < valid)
                    yb[(size_t)(row0 + row) * DM + nW + j * 16 + c] = acc[i * 4 + j][r];
            }
}

// ---- combine: out[t] = sum_k g_k*(y0[s_k]+y1[s_k]+b2[e_k]) --------------
__global__ __launch_bounds__(256) void combine_kernel(
    const float* __restrict__ y, const float* __restrict__ b2,
    const int* __restrict__ tok_slot, const float* __restrict__ tok_g,
    const int* __restrict__ tok_e, float* __restrict__ out)
{
    int tid = threadIdx.x;
    int t = blockIdx.x * 2 + (tid >> 7);
    int d = (tid & 127) * 4;
    int s0 = tok_slot[t * 2], s1 = tok_slot[t * 2 + 1];
    float g0 = tok_g[t * 2], g1 = tok_g[t * 2 + 1];
    int e0 = tok_e[t * 2], e1 = tok_e[t * 2 + 1];
    const float* y1 = y + (size_t)NSLOT * DM;
    f32x4 a0 = *(const f32x4*)&y[(size_t)s0 * DM + d];
    f32x4 a1 = *(const f32x4*)&y1[(size_t)s0 * DM + d];
    f32x4 b0 = *(const f32x4*)&y[(size_t)s1 * DM + d];
    f32x4 b1v = *(const f32x4*)&y1[(size_t)s1 * DM + d];
    f32x4 c0 = *(const f32x4*)&b2[e0 * DM + d];
    f32x4 c1 = *(const f32x4*)&b2[e1 * DM + d];
    f32x4 o;
    for (int i = 0; i < 4; ++i)
        o[i] = g0 * (a0[i] + a1[i] + c0[i]) + g1 * (b0[i] + b1v[i] + c1[i]);
    *(f32x4*)&out[(size_t)t * DM + d] = o;
}

extern "C" void kernel_launch(void* const* d_in, const int* in_sizes, int n_in,
                              void* d_out, int out_size, void* d_ws, size_t ws_size,
                              hipStream_t stream) {
    const float* x  = (const float*)d_in[0];
    const float* rw = (const float*)d_in[1];
    const float* rb = (const float*)d_in[2];
    const float* w1 = (const float*)d_in[3];
    const float* b1 = (const float*)d_in[4];
    const float* w2 = (const float*)d_in[5];
    const float* b2 = (const float*)d_in[6];
    float* out = (float*)d_out;

    char* ws = (char*)d_ws;
    size_t o = 0;
    unsigned short* h   = (unsigned short*)(ws + o); o += (size_t)NSLOT * DFF * 2;
    unsigned short* w1b = (unsigned short*)(ws + o); o += (size_t)NW * 2;
    unsigned short* w2b = (unsigned short*)(ws + o); o += (size_t)NW * 2;
    unsigned short* xb  = (unsigned short*)(ws + o); o += (size_t)T_TOK * DM * 2;
    int*   tok_e      = (int*)(ws + o);   o += (size_t)NSLOT * 4;
    float* tok_g      = (float*)(ws + o); o += (size_t)NSLOT * 4;
    int*   tok_slot   = (int*)(ws + o);   o += (size_t)NSLOT * 4;
    int*   slot_token = (int*)(ws + o);   o += (size_t)NSLOT * 4;
    int*   eoff       = (int*)(ws + o);
    // y (2 x 16 MB fp32) aliases w1b (64 MB): gemm1 is the last w1b reader
    float* y = (float*)w1b;

    convert_kernel<<<2 * NW / 8 / 256, 256, 0, stream>>>(w1, w2, w1b, w2b);
    router_kernel<<<T_TOK / 4, 256, 0, stream>>>(x, rw, rb, tok_e, tok_g, xb);
    compact_kernel<<<1, 256, 0, stream>>>(tok_e, slot_token, tok_slot, eoff);
    gemm1_kernel<<<dim3(DFF / 256, MAXT64), 256, 0, stream>>>(
        xb, w1b, b1, slot_token, eoff, h);
    gemm2_kernel<<<dim3(4, MAXT64), 256, 0, stream>>>(
        h, w2b, eoff, y);
    combine_kernel<<<T_TOK / 2, 256, 0, stream>>>(
        y, b2, tok_slot, tok_g, tok_e, out);
}

// Round 5
// 348.687 us; speedup vs baseline: 1.1399x; 1.1399x over previous
//
#include <hip/hip_runtime.h>
#include <stdint.h>

#define T_TOK 4096
#define DM    512
#define DFF   2048
#define NE    16
#define NSLOT (T_TOK * 2)
#define NW    (NE * DFF * DM)
#define MAXT64 144              // max sum ceil(cnt_e/64) = 128 + 16

typedef __attribute__((ext_vector_type(8))) short  bf16x8;
typedef __attribute__((ext_vector_type(4))) float  f32x4;
typedef __attribute__((ext_vector_type(8))) unsigned short us8;

static __device__ __forceinline__ unsigned short f2bf(float f) {
    unsigned int u = __float_as_uint(f);
    u += 0x7FFFu + ((u >> 16) & 1u);   // RNE
    return (unsigned short)(u >> 16);
}

static __device__ __forceinline__ void gload_lds16(const void* g, void* l) {
    __builtin_amdgcn_global_load_lds(
        (const __attribute__((address_space(1))) void*)g,
        (__attribute__((address_space(3))) void*)l, 16, 0, 0);
}

// ------------- convert: w1, w2 fp32 -> bf16 (memory-bound) ---------------
__global__ __launch_bounds__(256) void convert_kernel(
    const float* __restrict__ w1, const float* __restrict__ w2,
    unsigned short* __restrict__ w1b, unsigned short* __restrict__ w2b)
{
    size_t i = ((size_t)blockIdx.x * 256 + threadIdx.x) * 8;
    const float* src; unsigned short* dst;
    if (i < (size_t)NW) { src = w1 + i;        dst = w1b + i; }
    else                { src = w2 + (i - NW); dst = w2b + (i - NW); }
    f32x4 a = *(const f32x4*)src;
    f32x4 b = *(const f32x4*)(src + 4);
    us8 v;
    v[0] = f2bf(a.x); v[1] = f2bf(a.y); v[2] = f2bf(a.z); v[3] = f2bf(a.w);
    v[4] = f2bf(b.x); v[5] = f2bf(b.y); v[6] = f2bf(b.z); v[7] = f2bf(b.w);
    *(us8*)dst = v;
}

// ------- router: fp32 logits, softmax, top-2; also emits x in bf16 -------
__global__ __launch_bounds__(256) void router_kernel(
    const float* __restrict__ x, const float* __restrict__ rw,
    const float* __restrict__ rb, int* __restrict__ tok_e,
    float* __restrict__ tok_g, unsigned short* __restrict__ xb)
{
    __shared__ float rws[NE * DM];
    int tid = threadIdx.x;
    for (int i = 0; i < 8; ++i) {
        int idx = (tid + i * 256) * 4;
        *(f32x4*)&rws[idx] = *(const f32x4*)&rw[idx];
    }
    __syncthreads();

    int wid = tid >> 6, lane = tid & 63;
    int t = blockIdx.x * 4 + wid;

    float xv[8];
    const float* xp = x + (size_t)t * DM + lane * 8;
    *(f32x4*)&xv[0] = *(const f32x4*)xp;
    *(f32x4*)&xv[4] = *(const f32x4*)(xp + 4);

    us8 v;
    for (int i = 0; i < 8; ++i) v[i] = f2bf(xv[i]);
    *(us8*)&xb[(size_t)t * DM + lane * 8] = v;

    float acc[NE];
    for (int e = 0; e < NE; ++e) {
        const float* wp = &rws[e * DM + lane * 8];
        float a = 0.f;
        for (int i = 0; i < 8; ++i) a += xv[i] * wp[i];
        acc[e] = a;
    }
    for (int e = 0; e < NE; ++e) {
        float v2 = acc[e];
        for (int off = 32; off > 0; off >>= 1) v2 += __shfl_xor(v2, off);
        acc[e] = v2 + rb[e];
    }
    float m = acc[0];
    for (int e = 1; e < NE; ++e) m = fmaxf(m, acc[e]);
    float p[NE]; float s = 0.f;
    for (int e = 0; e < NE; ++e) { p[e] = expf(acc[e] - m); s += p[e]; }
    float inv = 1.f / s;
    int i0 = 0; float p0 = p[0];
    for (int e = 1; e < NE; ++e) if (p[e] > p0) { p0 = p[e]; i0 = e; }
    int i1 = (i0 == 0) ? 1 : 0; float p1 = p[i1];
    for (int e = 0; e < NE; ++e)
        if (e != i0 && p[e] > p1) { p1 = p[e]; i1 = e; }
    if (lane == 0) {
        tok_e[t * 2]     = i0;  tok_e[t * 2 + 1] = i1;
        tok_g[t * 2]     = p0 * inv;
        tok_g[t * 2 + 1] = p1 * inv;
    }
}

// -------- compaction: slot lists + 64-row tile prefix + tok->slot --------
// eoff: [0..15] row offset, [16..31] count, [32..47] tile_base, [48] total
__global__ __launch_bounds__(256) void compact_kernel(
    const int* __restrict__ tok_e, int* __restrict__ slot_token,
    int* __restrict__ tok_slot, int* __restrict__ eoff)
{
    __shared__ int cnt[NE], cur[NE];
    int tid = threadIdx.x;
    if (tid < NE) cnt[tid] = 0;
    __syncthreads();
    for (int t = tid; t < T_TOK; t += 256) {
        atomicAdd(&cnt[tok_e[t * 2]], 1);
        atomicAdd(&cnt[tok_e[t * 2 + 1]], 1);
    }
    __syncthreads();
    if (tid == 0) {
        int r = 0, tb = 0;
        for (int e = 0; e < NE; ++e) {
            eoff[e] = r; cur[e] = r; r += cnt[e];
            eoff[16 + e] = cnt[e];
            eoff[32 + e] = tb; tb += (cnt[e] + 63) >> 6;
        }
        eoff[48] = tb;
    }
    __syncthreads();
    for (int t = tid; t < T_TOK; t += 256) {
        for (int k = 0; k < 2; ++k) {
            int e = tok_e[t * 2 + k];
            int s = atomicAdd(&cur[e], 1);
            slot_token[s]       = t;
            tok_slot[t * 2 + k] = s;
        }
    }
}

// ---- fused MoE FFN: block = 64 slot-rows x one DFF-half -----------------
// Per pass (2x): hacc = x @ w1^T slice -> gelu -> H(LDS); y += H @ w2^T.
// h never hits HBM. y written per K-half; combine sums halves.
__global__ __launch_bounds__(512, 2) void fused_kernel(
    const unsigned short* __restrict__ xb, const unsigned short* __restrict__ w1b,
    const unsigned short* __restrict__ w2b, const float* __restrict__ b1,
    const int* __restrict__ slot_token, const int* __restrict__ eoff,
    float* __restrict__ y)
{
    __shared__ unsigned short X[64 * 512];     // 64 KB, swizzled
    __shared__ unsigned short H[64 * 512];     // 64 KB, swizzled
    __shared__ int tokrow[64];

    int tid = threadIdx.x, wave = tid >> 6, l = tid & 63;
    int c = l & 15, q = l >> 4;

    int ty = blockIdx.y;
    if (ty >= eoff[48]) return;
    int e = 0;
    #pragma unroll
    for (int k = 1; k < NE; ++k) e += (eoff[32 + k] <= ty) ? 1 : 0;
    int off = eoff[e], cnt = eoff[16 + e];
    int mt  = ty - eoff[32 + e];
    int row0  = off + mt * 64;
    int valid = cnt - mt * 64; if (valid > 64) valid = 64;
    int half = blockIdx.x;                     // DFF K-half
    int smax = off + cnt - 1;

    if (tid < 64) {
        int s = row0 + tid; if (s > smax) s = smax;
        tokrow[tid] = slot_token[s];
    }
    __syncthreads();

    // stage X: 64 rows x 512 cols bf16, chunk-XOR swizzled
    #pragma unroll
    for (int i = 0; i < 8; ++i) {
        int u = i * 512 + tid;
        int row = u >> 6, ch = u & 63;
        int sc = (ch & 56) | ((ch & 7) ^ (row & 7));
        gload_lds16(xb + (size_t)tokrow[row] * DM + sc * 8, &X[u * 8]);
    }

    f32x4 yacc[16];
    #pragma unroll
    for (int i = 0; i < 16; ++i) yacc[i] = (f32x4){0.f, 0.f, 0.f, 0.f};

    __syncthreads();                           // X ready (drains gload)

    for (int pass = 0; pass < 2; ++pass) {
        int nA = half * 1024 + pass * 512 + wave * 64;   // absolute DFF col
        const unsigned short* pB1[4];
        #pragma unroll
        for (int j = 0; j < 4; ++j)
            pB1[j] = w1b + ((size_t)e * DFF + nA + j * 16 + c) * DM + q * 8;

        f32x4 hacc[16];
        #pragma unroll
        for (int i = 0; i < 16; ++i) hacc[i] = (f32x4){0.f, 0.f, 0.f, 0.f};

        // phase A: hacc = X @ w1'
        #pragma unroll 2
        for (int kt = 0; kt < 8; ++kt) {
            #pragma unroll
            for (int ks = 0; ks < 2; ++ks) {
                bf16x8 af[4], bv[4];
                int sw = ((ks * 4 + q) ^ (c & 7)) * 8;
                #pragma unroll
                for (int i = 0; i < 4; ++i)
                    af[i] = *(bf16x8*)&X[(i * 16 + c) * 512 + kt * 64 + sw];
                #pragma unroll
                for (int j = 0; j < 4; ++j)
                    bv[j] = *(const bf16x8*)(pB1[j] + kt * 64 + ks * 32);
                #pragma unroll
                for (int i = 0; i < 4; ++i)
                    #pragma unroll
                    for (int j = 0; j < 4; ++j)
                        hacc[i * 4 + j] = __builtin_amdgcn_mfma_f32_16x16x32_bf16(
                            af[i], bv[j], hacc[i * 4 + j], 0, 0, 0);
            }
        }

        // bias + exact gelu -> H (LDS, swizzled); rel col = wave*64+j*16+c
        #pragma unroll
        for (int j = 0; j < 4; ++j) {
            float bias = b1[e * DFF + nA + j * 16 + c];
            int ncol = wave * 64 + j * 16 + c;
            int chunk = ncol >> 3;
            #pragma unroll
            for (int i = 0; i < 4; ++i) {
                f32x4 a = hacc[i * 4 + j];
                #pragma unroll
                for (int r = 0; r < 4; ++r) {
                    int rowl = i * 16 + q * 4 + r;
                    float z = a[r] + bias;
                    float g = 0.5f * z * (1.f + erff(z * 0.70710678118654752f));
                    H[rowl * 512 + ((chunk & 56) | ((chunk & 7) ^ (rowl & 7))) * 8
                      + (ncol & 7)] = f2bf(g);
                }
            }
        }
        __syncthreads();                       // H ready

        // phase B: yacc += H @ w2' (K-slice = this pass's 512 cols)
        const unsigned short* pB2[4];
        #pragma unroll
        for (int j = 0; j < 4; ++j)
            pB2[j] = w2b + ((size_t)e * DM + wave * 64 + j * 16 + c) * DFF
                     + half * 1024 + pass * 512 + q * 8;

        #pragma unroll 2
        for (int kt = 0; kt < 8; ++kt) {
            #pragma unroll
            for (int ks = 0; ks < 2; ++ks) {
                bf16x8 af[4], bv[4];
                int sw = ((ks * 4 + q) ^ (c & 7)) * 8;
                #pragma unroll
                for (int i = 0; i < 4; ++i)
                    af[i] = *(bf16x8*)&H[(i * 16 + c) * 512 + kt * 64 + sw];
                #pragma unroll
                for (int j = 0; j < 4; ++j)
                    bv[j] = *(const bf16x8*)(pB2[j] + kt * 64 + ks * 32);
                #pragma unroll
                for (int i = 0; i < 4; ++i)
                    #pragma unroll
                    for (int j = 0; j < 4; ++j)
                        yacc[i * 4 + j] = __builtin_amdgcn_mfma_f32_16x16x32_bf16(
                            af[i], bv[j], yacc[i * 4 + j], 0, 0, 0);
            }
        }
        __syncthreads();                       // H free for next pass
    }

    // store y partial for this K-half
    float* yb = y + (size_t)half * NSLOT * DM;
    #pragma unroll
    for (int i = 0; i < 4; ++i)
        #pragma unroll
        for (int j = 0; j < 4; ++j)
            #pragma unroll
            for (int r = 0; r < 4; ++r) {
                int rowl = i * 16 + q * 4 + r;
                if (rowl < valid)
                    yb[(size_t)(row0 + rowl) * DM + wave * 64 + j * 16 + c] =
                        yacc[i * 4 + j][r];
            }
}

// ---- combine: out[t] = sum_k g_k*(y0[s_k]+y1[s_k]+b2[e_k]) --------------
__global__ __launch_bounds__(256) void combine_kernel(
    const float* __restrict__ y, const float* __restrict__ b2,
    const int* __restrict__ tok_slot, const float* __restrict__ tok_g,
    const int* __restrict__ tok_e, float* __restrict__ out)
{
    int tid = threadIdx.x;
    int t = blockIdx.x * 2 + (tid >> 7);
    int d = (tid & 127) * 4;
    int s0 = tok_slot[t * 2], s1 = tok_slot[t * 2 + 1];
    float g0 = tok_g[t * 2], g1 = tok_g[t * 2 + 1];
    int e0 = tok_e[t * 2], e1 = tok_e[t * 2 + 1];
    const float* y1 = y + (size_t)NSLOT * DM;
    f32x4 a0 = *(const f32x4*)&y[(size_t)s0 * DM + d];
    f32x4 a1 = *(const f32x4*)&y1[(size_t)s0 * DM + d];
    f32x4 b0 = *(const f32x4*)&y[(size_t)s1 * DM + d];
    f32x4 b1v = *(const f32x4*)&y1[(size_t)s1 * DM + d];
    f32x4 c0 = *(const f32x4*)&b2[e0 * DM + d];
    f32x4 c1 = *(const f32x4*)&b2[e1 * DM + d];
    f32x4 o;
    for (int i = 0; i < 4; ++i)
        o[i] = g0 * (a0[i] + a1[i] + c0[i]) + g1 * (b0[i] + b1v[i] + c1[i]);
    *(f32x4*)&out[(size_t)t * DM + d] = o;
}

extern "C" void kernel_launch(void* const* d_in, const int* in_sizes, int n_in,
                              void* d_out, int out_size, void* d_ws, size_t ws_size,
                              hipStream_t stream) {
    const float* x  = (const float*)d_in[0];
    const float* rw = (const float*)d_in[1];
    const float* rb = (const float*)d_in[2];
    const float* w1 = (const float*)d_in[3];
    const float* b1 = (const float*)d_in[4];
    const float* w2 = (const float*)d_in[5];
    const float* b2 = (const float*)d_in[6];
    float* out = (float*)d_out;

    char* ws = (char*)d_ws;
    size_t o = 0;
    unsigned short* w1b = (unsigned short*)(ws + o); o += (size_t)NW * 2;
    unsigned short* w2b = (unsigned short*)(ws + o); o += (size_t)NW * 2;
    unsigned short* xb  = (unsigned short*)(ws + o); o += (size_t)T_TOK * DM * 2;
    float* y            = (float*)(ws + o);          o += (size_t)2 * NSLOT * DM * 4;
    int*   tok_e      = (int*)(ws + o);   o += (size_t)NSLOT * 4;
    float* tok_g      = (float*)(ws + o); o += (size_t)NSLOT * 4;
    int*   tok_slot   = (int*)(ws + o);   o += (size_t)NSLOT * 4;
    int*   slot_token = (int*)(ws + o);   o += (size_t)NSLOT * 4;
    int*   eoff       = (int*)(ws + o);

    convert_kernel<<<2 * NW / 8 / 256, 256, 0, stream>>>(w1, w2, w1b, w2b);
    router_kernel<<<T_TOK / 4, 256, 0, stream>>>(x, rw, rb, tok_e, tok_g, xb);
    compact_kernel<<<1, 256, 0, stream>>>(tok_e, slot_token, tok_slot, eoff);
    fused_kernel<<<dim3(2, MAXT64), 512, 0, stream>>>(
        xb, w1b, w2b, b1, slot_token, eoff, y);
    combine_kernel<<<T_TOK / 2, 256, 0, stream>>>(
        y, b2, tok_slot, tok_g, tok_e, out);
}